// Round 5
// baseline (733.688 us; speedup 1.0000x reference)
//
#include <hip/hip_runtime.h>

#define N_NODES 50000
#define N_EDGES 800000
#define IN_F 512
#define H_F 128
#define OUT_F 64

// ---------------- graph prep ----------------
// Harness ABI says integer -> const int*, but reference declares int64.
// Auto-detect: read first 256 entries as int64; all in [0,N_NODES) => int64
// (int32 data read as int64 would exceed N_NODES with overwhelming probability).

__global__ void detect_kernel(const void* __restrict__ edges, int* __restrict__ flag) {
    if (threadIdx.x == 0 && blockIdx.x == 0) {
        const long long* p = (const long long*)edges;
        int is64 = 1;
        for (int k = 0; k < 256; k++) {
            long long v = p[k];
            if (v < 0 || v >= N_NODES) { is64 = 0; break; }
        }
        flag[0] = is64;
    }
}

__device__ __forceinline__ int edge_at(const void* __restrict__ p, int e, int is64) {
    return is64 ? (int)((const long long*)p)[e] : ((const int*)p)[e];
}

__global__ void count_kernel(const void* __restrict__ src, const void* __restrict__ dst,
                             int* __restrict__ cs, int* __restrict__ cd,
                             const int* __restrict__ flag) {
    int is64 = flag[0];
    int e = blockIdx.x * 256 + threadIdx.x;
    if (e < N_EDGES) {
        atomicAdd(&cs[edge_at(src, e, is64)], 1);
        atomicAdd(&cd[edge_at(dst, e, is64)], 1);
    }
}

// per-block exclusive scan (1024 elems/block), Hillis-Steele in LDS
__global__ void scan_kernel(const int* __restrict__ in, int* __restrict__ exc,
                            int* __restrict__ bsums, int n) {
    __shared__ int tmp[1024];
    int tid = threadIdx.x;
    int gid = blockIdx.x * 1024 + tid;
    int v = (gid < n) ? in[gid] : 0;
    tmp[tid] = v;
    __syncthreads();
    for (int off = 1; off < 1024; off <<= 1) {
        int t = (tid >= off) ? tmp[tid - off] : 0;
        __syncthreads();
        tmp[tid] += t;
        __syncthreads();
    }
    if (gid < n) exc[gid] = tmp[tid] - v;   // exclusive
    if (tid == 1023) bsums[blockIdx.x] = tmp[1023];
}

// rp/cur from scanned counts; also computes both norm vectors (fused, one less launch)
__global__ void finalize_kernel(const int* __restrict__ exc, const int* __restrict__ bexc,
                                int* __restrict__ rp, int* __restrict__ cur,
                                const int* __restrict__ cs, const int* __restrict__ cd,
                                float* __restrict__ ns, float* __restrict__ nd) {
    int i = blockIdx.x * 256 + threadIdx.x;
    if (i < N_NODES) {
        int v = exc[i] + bexc[i >> 10];
        rp[i] = v;
        cur[i] = v;
        if (i == 0) rp[N_NODES] = N_EDGES;
        ns[i] = 1.0f / sqrtf(fmaxf((float)cs[i], 1.0f));
        nd[i] = 1.0f / sqrtf(fmaxf((float)cd[i], 1.0f));
    }
}

__global__ void fill_kernel(const void* __restrict__ src, const void* __restrict__ dst,
                            int* __restrict__ cur, int* __restrict__ col,
                            const int* __restrict__ flag) {
    int is64 = flag[0];
    int e = blockIdx.x * 256 + threadIdx.x;
    if (e < N_EDGES) {
        int d = edge_at(dst, e, is64);
        int pos = atomicAdd(&cur[d], 1);
        col[pos] = edge_at(src, e, is64);
    }
}

// ---------------- GEMM: C[M,N] = norm[row] * (A @ W), fp32 vector ----------------
// norm commutes through the matmul (row scale), applied in epilogue.
// BM=128 rows/block, 256 threads. Thread (tx,ty): 8 cols x RT rows register tile.
// Ast: transposed A tile [32][BM+4]  (a-frag read = broadcast groups, conflict-free)
// Ws : skewed row-major  [32][SW]    slot f -> f+(f>>3): frag reads 2-way (free, m136)
// COPY: layer-1 fuses the x-passthrough output (each x element staged exactly once).

__device__ __forceinline__ constexpr int swz(int f) { return f + (f >> 3); }

template <int N, int BM, bool COPY>
__global__ __launch_bounds__(256) void gemm_norm(const float* __restrict__ A, const float* __restrict__ W,
                                                 const float* __restrict__ norm, float* __restrict__ C,
                                                 int K, float* __restrict__ xc) {
    constexpr int TX = N / 8;            // threads across cols (16 for N=128, 8 for N=64)
    constexpr int TY = 256 / TX;         // threads across rows (16 / 32)
    constexpr int RT = BM / TY;          // rows per thread (8 / 4)
    constexpr int NF4 = N / 4;           // float4 slots per W row (32 / 16)
    constexpr int SA = BM + 4;           // Ast row stride (floats), %4==0 keeps b128 aligned
    constexpr int SW = (swz(NF4 - 1) + 2 + 3) / 4 * 4 * 4;  // Ws row stride (floats), mult of 4

    __shared__ float Ast[32 * SA];
    __shared__ float Ws[32 * SW];

    const int t = threadIdx.x;
    const int tx = t % TX, ty = t / TX;
    const int m0 = blockIdx.x * BM;

    float acc[RT][8];
    #pragma unroll
    for (int i = 0; i < RT; i++)
        #pragma unroll
        for (int j = 0; j < 8; j++) acc[i][j] = 0.f;

    for (int k0 = 0; k0 < K; k0 += 32) {
        // stage A transposed: BM rows x 32 k
        #pragma unroll
        for (int p = 0; p < BM * 32 / 4 / 256; p++) {
            int idx = t + p * 256;           // float4 id
            int r = idx >> 3;                // row in tile 0..BM-1
            int c = (idx & 7) << 2;          // k within tile 0..28
            int row = m0 + r;
            float4 v = make_float4(0.f, 0.f, 0.f, 0.f);
            if (row < N_NODES) {
                v = *(const float4*)&A[(size_t)row * K + k0 + c];
                if (COPY) *(float4*)&xc[(size_t)row * K + k0 + c] = v;
            }
            Ast[(c + 0) * SA + r] = v.x;
            Ast[(c + 1) * SA + r] = v.y;
            Ast[(c + 2) * SA + r] = v.z;
            Ast[(c + 3) * SA + r] = v.w;
        }
        // stage W skewed: 32 k x N
        #pragma unroll
        for (int p = 0; p < 32 * NF4 / 256; p++) {
            int idx = t + p * 256;
            int r = idx / NF4;
            int f = idx % NF4;
            float4 wv = *(const float4*)&W[(size_t)(k0 + r) * N + f * 4];
            *(float4*)&Ws[r * SW + swz(f) * 4] = wv;
        }
        __syncthreads();
        #pragma unroll 8
        for (int kk = 0; kk < 32; kk++) {
            float a[RT], w[8];
            #pragma unroll
            for (int r4 = 0; r4 < RT / 4; r4++)
                *(float4*)&a[r4 * 4] = *(const float4*)&Ast[kk * SA + ty * RT + r4 * 4];
            int f0 = tx * 2;
            *(float4*)&w[0] = *(const float4*)&Ws[kk * SW + (f0 + (f0 >> 3)) * 4];
            *(float4*)&w[4] = *(const float4*)&Ws[kk * SW + (f0 + 1 + ((f0 + 1) >> 3)) * 4];
            #pragma unroll
            for (int i = 0; i < RT; i++)
                #pragma unroll
                for (int j = 0; j < 8; j++) acc[i][j] = fmaf(a[i], w[j], acc[i][j]);
        }
        __syncthreads();
    }
    #pragma unroll
    for (int i = 0; i < RT; i++) {
        int row = m0 + ty * RT + i;
        if (row < N_NODES) {
            float s = norm[row];
            float4 o0 = make_float4(acc[i][0] * s, acc[i][1] * s, acc[i][2] * s, acc[i][3] * s);
            float4 o1 = make_float4(acc[i][4] * s, acc[i][5] * s, acc[i][6] * s, acc[i][7] * s);
            *(float4*)&C[(size_t)row * N + tx * 8] = o0;
            *(float4*)&C[(size_t)row * N + tx * 8 + 4] = o1;
        }
    }
}

// ---------------- SpMM: out[i,:] = relu?(nd[i]*sum_{e in row i} h[col[e],:] + b) ----------
// ONE WAVE PER NODE. FEAT=128: lane holds float2 (64 lanes x 8B = 512B/instr);
// FEAT=64: lane holds 1 float. i wave-uniform via readfirstlane -> rp/col scalar loads.
// HID: fused conditional hidden-embedding copy (emb low word correct for int32/int64).

template <int FEAT, bool RELU, bool HID>
__global__ __launch_bounds__(256) void spmm_kernel(
        const float* __restrict__ h, const int* __restrict__ rp,
        const int* __restrict__ col, const float* __restrict__ nd,
        const float* __restrict__ bias, float* __restrict__ out,
        float* __restrict__ hid, const int* __restrict__ emb, int layer) {
    constexpr int VEC = FEAT / 64;       // 2 or 1
    int i = blockIdx.x * 4 + (threadIdx.x >> 6);
    i = __builtin_amdgcn_readfirstlane(i);
    if (i >= N_NODES) return;
    int lane = threadIdx.x & 63;
    int beg = rp[i], end = rp[i + 1];

    if (VEC == 2) {
        float ax = 0.f, ay = 0.f;
        int e = beg;
        for (; e + 4 <= end; e += 4) {
            int c0 = col[e], c1 = col[e + 1], c2 = col[e + 2], c3 = col[e + 3];
            float2 v0 = *(const float2*)&h[(size_t)c0 * FEAT + lane * 2];
            float2 v1 = *(const float2*)&h[(size_t)c1 * FEAT + lane * 2];
            float2 v2 = *(const float2*)&h[(size_t)c2 * FEAT + lane * 2];
            float2 v3 = *(const float2*)&h[(size_t)c3 * FEAT + lane * 2];
            ax += v0.x + v1.x + v2.x + v3.x;
            ay += v0.y + v1.y + v2.y + v3.y;
        }
        for (; e < end; e++) {
            float2 v = *(const float2*)&h[(size_t)col[e] * FEAT + lane * 2];
            ax += v.x; ay += v.y;
        }
        float s = nd[i];
        float2 b = *(const float2*)&bias[lane * 2];
        float vx = fmaf(ax, s, b.x), vy = fmaf(ay, s, b.y);
        if (RELU) { vx = fmaxf(vx, 0.f); vy = fmaxf(vy, 0.f); }
        float2 o = make_float2(vx, vy);
        *(float2*)&out[(size_t)i * FEAT + lane * 2] = o;
        if (HID) {
            if (emb[0] == layer) *(float2*)&hid[(size_t)i * FEAT + lane * 2] = o;
        }
    } else {
        float acc = 0.f;
        int e = beg;
        for (; e + 4 <= end; e += 4) {
            int c0 = col[e], c1 = col[e + 1], c2 = col[e + 2], c3 = col[e + 3];
            acc += h[(size_t)c0 * FEAT + lane];
            acc += h[(size_t)c1 * FEAT + lane];
            acc += h[(size_t)c2 * FEAT + lane];
            acc += h[(size_t)c3 * FEAT + lane];
        }
        for (; e < end; e++) acc += h[(size_t)col[e] * FEAT + lane];
        float v = fmaf(acc, nd[i], bias[lane]);
        if (RELU) v = fmaxf(v, 0.f);
        out[(size_t)i * FEAT + lane] = v;
        if (HID) {
            if (emb[0] == layer) hid[(size_t)i * FEAT + lane] = v;
        }
    }
}

// ---------------- launch ----------------

extern "C" void kernel_launch(void* const* d_in, const int* in_sizes, int n_in,
                              void* d_out, int out_size, void* d_ws, size_t ws_size,
                              hipStream_t stream) {
    const float* x = (const float*)d_in[0];
    const void* src = d_in[1];
    const void* dst = d_in[2];
    const float* W1 = (const float*)d_in[3];  const float* b1 = (const float*)d_in[4];
    const float* W2 = (const float*)d_in[5];  const float* b2 = (const float*)d_in[6];
    const float* W3 = (const float*)d_in[7];  const float* b3 = (const float*)d_in[8];
    const float* W4 = (const float*)d_in[9];  const float* b4 = (const float*)d_in[10];
    const int* emb = (const int*)d_in[11];    // low word correct for int32 or int64
    float* out = (float*)d_out;

    // workspace carve-up (~53 MB)
    char* w = (char*)d_ws;
    int* cnt_src = (int*)w;  w += 51200 * 4;
    int* cnt_dst = (int*)w;  w += 51200 * 4;
    float* norm_src = (float*)w; w += 51200 * 4;
    float* norm_dst = (float*)w; w += 51200 * 4;
    int* exc = (int*)w;      w += 51200 * 4;
    int* bsums = (int*)w;    w += 1024 * 4;
    int* bexc = (int*)w;     w += 1024 * 4;
    int* bdummy = (int*)w;   w += 1024 * 4;
    int* dflag = (int*)w;    w += 1024 * 4;
    int* rp = (int*)w;       w += 51200 * 4;
    int* cur = (int*)w;      w += 51200 * 4;
    int* col = (int*)w;      w += 800768 * 4;
    float* gbuf = (float*)w; w += (size_t)6400000 * 4;   // GEMM output (pre-aggregation)
    float* hbuf = (float*)w; w += (size_t)6400000 * 4;   // SpMM output

    // graph prep
    hipMemsetAsync(cnt_src, 0, 2 * 51200 * 4, stream);   // cnt_src + cnt_dst contiguous
    detect_kernel<<<1, 64, 0, stream>>>(dst, dflag);
    count_kernel<<<3125, 256, 0, stream>>>(src, dst, cnt_src, cnt_dst, dflag);
    scan_kernel<<<49, 1024, 0, stream>>>(cnt_dst, exc, bsums, N_NODES);
    scan_kernel<<<1, 1024, 0, stream>>>(bsums, bexc, bdummy, 49);
    finalize_kernel<<<196, 256, 0, stream>>>(exc, bexc, rp, cur,
                                             cnt_src, cnt_dst, norm_src, norm_dst);
    fill_kernel<<<3125, 256, 0, stream>>>(src, dst, cur, col, dflag);

    const int GB = (N_NODES + 127) / 128;   // 391 blocks
    const int SB = (N_NODES + 3) / 4;       // 12500 blocks (4 waves = 4 nodes each)
    float* hid = out + (size_t)N_NODES * OUT_F;
    float* xcopy = hid + (size_t)N_NODES * H_F;

    // layer 1: 512 -> 128, relu  (fuses x passthrough copy into A-staging)
    gemm_norm<128, 128, true><<<GB, 256, 0, stream>>>(x, W1, norm_src, gbuf, IN_F, xcopy);
    spmm_kernel<128, true, true><<<SB, 256, 0, stream>>>(gbuf, rp, col, norm_dst, b1, hbuf, hid, emb, 1);

    // layer 2: 128 -> 128, relu
    gemm_norm<128, 128, false><<<GB, 256, 0, stream>>>(hbuf, W2, norm_src, gbuf, H_F, nullptr);
    spmm_kernel<128, true, true><<<SB, 256, 0, stream>>>(gbuf, rp, col, norm_dst, b2, hbuf, hid, emb, 2);

    // layer 3: 128 -> 128, relu
    gemm_norm<128, 128, false><<<GB, 256, 0, stream>>>(hbuf, W3, norm_src, gbuf, H_F, nullptr);
    spmm_kernel<128, true, true><<<SB, 256, 0, stream>>>(gbuf, rp, col, norm_dst, b3, hbuf, hid, emb, 3);

    // layer 4: 128 -> 64, no relu, straight into d_out
    gemm_norm<64, 128, false><<<GB, 256, 0, stream>>>(hbuf, W4, norm_src, gbuf, H_F, nullptr);
    spmm_kernel<64, false, false><<<SB, 256, 0, stream>>>(gbuf, rp, col, norm_dst, b4, out, nullptr, nullptr, 0);
}